// Round 6
// baseline (479.940 us; speedup 1.0000x reference)
//
#include <hip/hip_runtime.h>
#include <math.h>

typedef __attribute__((ext_vector_type(8))) short short8;
typedef __bf16 bf16x8 __attribute__((ext_vector_type(8)));
typedef __attribute__((ext_vector_type(4))) float f32x4;
typedef __attribute__((ext_vector_type(16))) float f32x16;

__device__ inline short f2bf(float f) {
    unsigned u = __builtin_bit_cast(unsigned, f);
    u += 0x7fff + ((u >> 16) & 1);   // round-to-nearest-even
    return (short)(u >> 16);
}
__device__ inline float bf2f(short h) {
    return __builtin_bit_cast(float, ((unsigned)(unsigned short)h) << 16);
}
__device__ inline float gelu_f(float x) {
    return 0.5f * x * (1.f + erff(x * 0.70710678118654752f));
}

// ---------------------------------------------------------------------------
// W f32 [K][N] -> Wt bf16 [N][K]
// ---------------------------------------------------------------------------
__global__ __launch_bounds__(256) void wcast_t(
    const float* __restrict__ W, short* __restrict__ Wt, int K, int N)
{
    __shared__ float T[32][33];
    int k0 = blockIdx.y * 32, n0 = blockIdx.x * 32;
    int tid = threadIdx.x;
    int r = tid >> 3, c4 = (tid & 7) * 4;
    float4 v = *(const float4*)&W[(size_t)(k0 + r) * N + n0 + c4];
    T[r][c4 + 0] = v.x; T[r][c4 + 1] = v.y; T[r][c4 + 2] = v.z; T[r][c4 + 3] = v.w;
    __syncthreads();
    short4 o;
    o.x = f2bf(T[c4 + 0][r]);
    o.y = f2bf(T[c4 + 1][r]);
    o.z = f2bf(T[c4 + 2][r]);
    o.w = f2bf(T[c4 + 3][r]);
    *(short4*)&Wt[(size_t)(n0 + r) * K + k0 + c4] = o;
}

// W f32 [K][N] -> W3t bf16 [N][3K] = [hi | lo | hi]
__global__ __launch_bounds__(256) void wcast_t3(
    const float* __restrict__ W, short* __restrict__ W3t, int K, int N)
{
    __shared__ float T[32][33];
    int k0 = blockIdx.y * 32, n0 = blockIdx.x * 32;
    int tid = threadIdx.x;
    int r = tid >> 3, c4 = (tid & 7) * 4;
    float4 v = *(const float4*)&W[(size_t)(k0 + r) * N + n0 + c4];
    T[r][c4 + 0] = v.x; T[r][c4 + 1] = v.y; T[r][c4 + 2] = v.z; T[r][c4 + 3] = v.w;
    __syncthreads();
    short4 hi, lo;
    float f;
    f = T[c4 + 0][r]; hi.x = f2bf(f); lo.x = f2bf(f - bf2f(hi.x));
    f = T[c4 + 1][r]; hi.y = f2bf(f); lo.y = f2bf(f - bf2f(hi.y));
    f = T[c4 + 2][r]; hi.z = f2bf(f); lo.z = f2bf(f - bf2f(hi.z));
    f = T[c4 + 3][r]; hi.w = f2bf(f); lo.w = f2bf(f - bf2f(hi.w));
    short* d = W3t + (size_t)(n0 + r) * 3 * K + k0 + c4;
    *(short4*)d = hi;
    *(short4*)(d + K) = lo;
    *(short4*)(d + 2 * K) = hi;
}

// ---------------------------------------------------------------------------
// bf16 MFMA GEMM, B^T layout (proven R4).
// ---------------------------------------------------------------------------
template <int AF32, int ACT, int OUTF32>
__global__ __launch_bounds__(256) void gemm_bt(
    const void* A0_, const void* A1_,
    const short* __restrict__ B0, const short* __restrict__ B1,
    const float* __restrict__ b0, const float* __restrict__ b1,
    void* C0_, void* C1_,
    float s0, float s1, int N, int K)
{
    const int z = blockIdx.z;
    const void* A_ = z ? A1_ : A0_;
    const short* B = z ? B1 : B0;
    const float* bias = z ? b1 : b0;
    void* C_ = z ? C1_ : C0_;
    const float scale = z ? s1 : s0;

    const int bm = blockIdx.y * 128;
    const int bn = blockIdx.x * 128;
    const int tid = threadIdx.x;
    const int w = tid >> 6;
    const int lane = tid & 63;
    const int l15 = lane & 15, quad = lane >> 4;
    const int wm = (w >> 1) * 64, wn = (w & 1) * 64;

    __shared__ __align__(16) short As[128 * 32];
    __shared__ __align__(16) short Bs[128 * 32];

    f32x4 acc[4][4];
#pragma unroll
    for (int mt = 0; mt < 4; ++mt)
#pragma unroll
        for (int nt = 0; nt < 4; ++nt) acc[mt][nt] = (f32x4){0.f, 0.f, 0.f, 0.f};

    const int ga0 = tid * 2;

    for (int k0 = 0; k0 < K; k0 += 32) {
#pragma unroll
        for (int i = 0; i < 2; ++i) {
            int ga = ga0 + i;
            int row = ga >> 2, g = ga & 3;
            short8 aval;
            if (AF32) {
                const float* ap = (const float*)A_ + (size_t)(bm + row) * K + k0 + g * 8;
                float4 f0 = *(const float4*)ap;
                float4 f1 = *(const float4*)(ap + 4);
                aval[0] = f2bf(f0.x); aval[1] = f2bf(f0.y);
                aval[2] = f2bf(f0.z); aval[3] = f2bf(f0.w);
                aval[4] = f2bf(f1.x); aval[5] = f2bf(f1.y);
                aval[6] = f2bf(f1.z); aval[7] = f2bf(f1.w);
            } else {
                aval = *(const short8*)((const short*)A_ + (size_t)(bm + row) * K + k0 + g * 8);
            }
            *(short8*)(void*)&As[row * 32 + ((g ^ (row & 3)) * 8)] = aval;
            short8 bval = *(const short8*)(const void*)&B[(size_t)(bn + row) * K + k0 + g * 8];
            *(short8*)(void*)&Bs[row * 32 + ((g ^ (row & 3)) * 8)] = bval;
        }
        __syncthreads();

        bf16x8 af[4], bfr[4];
#pragma unroll
        for (int t = 0; t < 4; ++t) {
            af[t] = __builtin_bit_cast(bf16x8,
                *(const short8*)(const void*)&As[(wm + t * 16 + l15) * 32 + ((quad ^ (l15 & 3)) * 8)]);
            bfr[t] = __builtin_bit_cast(bf16x8,
                *(const short8*)(const void*)&Bs[(wn + t * 16 + l15) * 32 + ((quad ^ (l15 & 3)) * 8)]);
        }
#pragma unroll
        for (int mt = 0; mt < 4; ++mt)
#pragma unroll
            for (int nt = 0; nt < 4; ++nt)
                acc[mt][nt] = __builtin_amdgcn_mfma_f32_16x16x32_bf16(af[mt], bfr[nt], acc[mt][nt], 0, 0, 0);
        __syncthreads();
    }

    float bv[4];
#pragma unroll
    for (int nt = 0; nt < 4; ++nt) bv[nt] = bias[bn + wn + nt * 16 + l15];
#pragma unroll
    for (int mt = 0; mt < 4; ++mt)
#pragma unroll
        for (int r = 0; r < 4; ++r) {
            int row = bm + wm + mt * 16 + quad * 4 + r;
#pragma unroll
            for (int nt = 0; nt < 4; ++nt) {
                float v = acc[mt][nt][r] + bv[nt];
                if (ACT) v = gelu_f(v);
                v *= scale;
                int col = bn + wn + nt * 16 + l15;
                if (OUTF32) ((float*)C_)[(size_t)row * N + col] = v;
                else        ((short*)C_)[(size_t)row * N + col] = f2bf(v);
            }
        }
}

// ---------------------------------------------------------------------------
// K repack: kbb bf16 [8192][256] -> kfr frag-major (proven R5)
// ---------------------------------------------------------------------------
__global__ __launch_bounds__(256) void repack_k(
    const short* __restrict__ kb, short* __restrict__ kfr)
{
    const int kt = blockIdx.x, bh = blockIdx.y;
    const int b = bh >> 3, h = bh & 7;
    const int t = threadIdx.x;
    const int c = t >> 6, l = t & 63;
    const int nt = c >> 1, ks = c & 1;
    int key = kt * 64 + nt * 32 + (l & 31);
    int k = ks * 16 + (l >> 5) * 8;
    short8 v = *(const short8*)(const void*)&kb[(size_t)(b * 4096 + key) * 256 + h * 32 + k];
    *(short8*)(void*)&kfr[((((size_t)bh * 64 + kt) * 4 + c) * 64 + l) * 8] = v;
}

// ---------------------------------------------------------------------------
// V repack: vbb bf16 [8192][512] -> vfr frag-major (proven R5)
// ---------------------------------------------------------------------------
__global__ __launch_bounds__(256) void repack_v(
    const short* __restrict__ vbb, short* __restrict__ vfr)
{
    const int kt = blockIdx.x, bh = blockIdx.y;
    const int b = bh >> 3, h = bh & 7;
    const int t = threadIdx.x;
    __shared__ short Vt[64][72];   // [key][dk]

#pragma unroll
    for (int it = 0; it < 2; ++it) {
        int idx = t + it * 256;
        int keyr = idx >> 3, c8 = (idx & 7) * 8;
        *(short8*)(void*)&Vt[keyr][c8] =
            *(const short8*)(const void*)&vbb[(size_t)(b * 4096 + kt * 64 + keyr) * 512 + h * 64 + c8];
    }
    __syncthreads();
#pragma unroll
    for (int it = 0; it < 2; ++it) {
        int chunk = (t >> 6) * 2 + it;
        int l = t & 63;
        int dt = chunk >> 2, ks = chunk & 3;
        short8 o;
#pragma unroll
        for (int j = 0; j < 8; ++j)
            o[j] = Vt[ks * 16 + (l >> 5) * 8 + j][dt * 32 + (l & 31)];
        *(short8*)(void*)&vfr[((((size_t)bh * 64 + kt) * 8 + chunk) * 64 + l) * 8] = o;
    }
}

// ---------------------------------------------------------------------------
// Flash attention, 32x32x16 MFMA, key-split waves.
// Block = 4 waves = 64 q rows; wave w: q-half qh=w&1 (32 rows), key-half
// kh=w>>1 (32 of each 64-key tile). Grid 64x16 = 1024 blocks.
// No-max softmax via raw v_exp (q pre-scaled by log2(e)/sqrt(32)).
// Epilogue: LDS reduction of (O,l) partials across the two key-halves.
// ---------------------------------------------------------------------------
__global__ __launch_bounds__(256) void flash_mfma32(
    const short* __restrict__ qb, const short* __restrict__ kfr,
    const short* __restrict__ vfr, short* __restrict__ xb3)
{
    const int qt = blockIdx.x;   // 0..63, 64 q rows
    const int bh = blockIdx.y;   // 0..15
    const int b = bh >> 3, h = bh & 7;
    const int tid = threadIdx.x;
    const int w = tid >> 6;
    const int lane = tid & 63;
    const int l31 = lane & 31;
    const int half = lane >> 5;
    const int qh = w & 1;        // q-half
    const int kh = w >> 1;       // key-half

    // 12288 B KV (12 chunks x 512 shorts) + 4 x 2560 B per-wave P = 22528 B.
    // Epilogue reuses the whole region as f32 red[64 q][66].
    __shared__ __align__(16) char smem[22528];
    short* KV = (short*)smem;                          // chunks 0..3 K, 4..11 V
    short* Pw = (short*)(smem + 12288 + w * 2560);     // [32 q][32 key + 8 pad]

    // Q A-frags for this wave's 32 q rows (m = l31), k-halves 0/1
    const short* qrow = qb + (size_t)(b * 4096 + qt * 64 + qh * 32 + l31) * 256 + h * 32 + half * 8;
    bf16x8 qf0 = __builtin_bit_cast(bf16x8, *(const short8*)(const void*)qrow);
    bf16x8 qf1 = __builtin_bit_cast(bf16x8, *(const short8*)(const void*)(qrow + 16));

    f32x16 O0{}, O1{};
    float la[16];
#pragma unroll
    for (int r = 0; r < 16; ++r) la[r] = 0.f;

    const short* kbase = kfr + ((size_t)bh * 64) * 4 * 512;
    const short* vbase = vfr + ((size_t)bh * 64) * 8 * 512;

#pragma unroll 1
    for (int kt = 0; kt < 64; ++kt) {
        __syncthreads();   // previous iteration's KV reads done
#pragma unroll
        for (int i = 0; i < 3; ++i) {
            int c = w * 3 + i;
            const short* g = (c < 4)
                ? (kbase + ((size_t)kt * 4 + c) * 512 + lane * 8)
                : (vbase + ((size_t)kt * 8 + (c - 4)) * 512 + lane * 8);
            *(short8*)(void*)&KV[c * 512 + lane * 8] = *(const short8*)(const void*)g;
        }
        __syncthreads();

        // QK^T: this wave's 32 q x 32 keys (K chunks kh*2, kh*2+1)
        f32x16 zero{};
        bf16x8 kf0 = __builtin_bit_cast(bf16x8,
            *(const short8*)(const void*)&KV[(kh * 2 + 0) * 512 + lane * 8]);
        bf16x8 kf1 = __builtin_bit_cast(bf16x8,
            *(const short8*)(const void*)&KV[(kh * 2 + 1) * 512 + lane * 8]);
        f32x16 s = __builtin_amdgcn_mfma_f32_32x32x16_bf16(qf0, kf0, zero, 0, 0, 0);
        s = __builtin_amdgcn_mfma_f32_32x32x16_bf16(qf1, kf1, s, 0, 0, 0);

        // exp (scores bounded, no max) + l accumulate + P -> LDS bf16
#pragma unroll
        for (int r = 0; r < 16; ++r) {
            float p = __builtin_amdgcn_exp2f(s[r]);
            la[r] += p;
            int qr = (r & 3) + 8 * (r >> 2) + 4 * half;  // C-layout row
            Pw[qr * 40 + l31] = f2bf(p);
        }

        // PV: O[32 q][64 dk] += P[32 q][32 key] @ V[32 key][64 dk]
        bf16x8 pf0 = __builtin_bit_cast(bf16x8,
            *(const short8*)(const void*)&Pw[l31 * 40 + 0 * 16 + half * 8]);
        bf16x8 pf1 = __builtin_bit_cast(bf16x8,
            *(const short8*)(const void*)&Pw[l31 * 40 + 1 * 16 + half * 8]);
        bf16x8 vf;
        vf = __builtin_bit_cast(bf16x8,
            *(const short8*)(const void*)&KV[(4 + 0 * 4 + kh * 2 + 0) * 512 + lane * 8]);
        O0 = __builtin_amdgcn_mfma_f32_32x32x16_bf16(pf0, vf, O0, 0, 0, 0);
        vf = __builtin_bit_cast(bf16x8,
            *(const short8*)(const void*)&KV[(4 + 0 * 4 + kh * 2 + 1) * 512 + lane * 8]);
        O0 = __builtin_amdgcn_mfma_f32_32x32x16_bf16(pf1, vf, O0, 0, 0, 0);
        vf = __builtin_bit_cast(bf16x8,
            *(const short8*)(const void*)&KV[(4 + 1 * 4 + kh * 2 + 0) * 512 + lane * 8]);
        O1 = __builtin_amdgcn_mfma_f32_32x32x16_bf16(pf0, vf, O1, 0, 0, 0);
        vf = __builtin_bit_cast(bf16x8,
            *(const short8*)(const void*)&KV[(4 + 1 * 4 + kh * 2 + 1) * 512 + lane * 8]);
        O1 = __builtin_amdgcn_mfma_f32_32x32x16_bf16(pf1, vf, O1, 0, 0, 0);
    }

    // ---- epilogue: cross-wave (key-half) reduction, then store ----
    // in-wave l reduce over the 32 col-lanes (all xors preserve bit5)
#pragma unroll
    for (int r = 0; r < 16; ++r) {
        float t = la[r];
        t += __shfl_xor(t, 1);
        t += __shfl_xor(t, 2);
        t += __shfl_xor(t, 4);
        t += __shfl_xor(t, 8);
        t += __shfl_xor(t, 16);
        la[r] = t;
    }

    __syncthreads();   // all KV/P reads done; smem reusable
    float* red = (float*)smem;   // [64 q][66]: 64*66*4 = 16896 B
    if (kh == 1) {
#pragma unroll
        for (int r = 0; r < 16; ++r) {
            int qr = qh * 32 + (r & 3) + 8 * (r >> 2) + 4 * half;
            red[qr * 66 + l31] = O0[r];
            red[qr * 66 + 32 + l31] = O1[r];
            if (l31 == 0) red[qr * 66 + 64] = la[r];
        }
    }
    __syncthreads();
    if (kh == 0) {
#pragma unroll
        for (int r = 0; r < 16; ++r) {
            int qrl = (r & 3) + 8 * (r >> 2) + 4 * half;
            int qr = qh * 32 + qrl;
            float o0 = O0[r] + red[qr * 66 + l31];
            float o1 = O1[r] + red[qr * 66 + 32 + l31];
            float inv = 1.f / (la[r] + red[qr * 66 + 64]);
            size_t row = (size_t)(b * 4096 + qt * 64 + qr);
            float x0 = o0 * inv, x1 = o1 * inv;
            short hi0 = f2bf(x0), hi1 = f2bf(x1);
            short lo0 = f2bf(x0 - bf2f(hi0)), lo1 = f2bf(x1 - bf2f(hi1));
            short* d = xb3 + row * 1536 + h * 64 + l31;
            d[0] = hi0;   d[32] = hi1;
            d[512] = hi0; d[544] = hi1;
            d[1024] = lo0; d[1056] = lo1;
        }
    }
}

// ---------------------------------------------------------------------------
extern "C" void kernel_launch(void* const* d_in, const int* in_sizes, int n_in,
                              void* d_out, int out_size, void* d_ws, size_t ws_size,
                              hipStream_t stream)
{
    const float* query = (const float*)d_in[0];
    const float* key   = (const float*)d_in[1];
    const float* value = (const float*)d_in[2];
    const float* Wq1   = (const float*)d_in[3];
    const float* bq1   = (const float*)d_in[4];
    const float* Wq2   = (const float*)d_in[5];
    const float* bq2   = (const float*)d_in[6];
    const float* Wk1   = (const float*)d_in[7];
    const float* bk1   = (const float*)d_in[8];
    const float* Wk2   = (const float*)d_in[9];
    const float* bk2   = (const float*)d_in[10];
    const float* Wv    = (const float*)d_in[11];
    const float* bv    = (const float*)d_in[12];
    const float* Wo    = (const float*)d_in[13];
    const float* bo    = (const float*)d_in[14];
    float* out = (float*)d_out;

    // Workspace (bytes), total 68 MB:
    char* ws = (char*)d_ws;
    short* H1q  = (short*)(ws + 0);            // 16 MB   (dead after mlp2)
    short* H1k  = (short*)(ws + 16777216);     // 16 MB   (dead after mlp2)
    short* xb3  = (short*)(ws + 0);            // 25,165,824 (overlays H1)
    short* qbb  = (short*)(ws + 33554432);     // 4 MB
    short* kbb  = (short*)(ws + 37748736);     // 4 MB
    short* vbb  = (short*)(ws + 41943040);     // 8 MB
    short* kfr  = (short*)(ws + 50331648);     // 4 MB
    short* vfr  = (short*)(ws + 54525952);     // 8 MB
    short* Wq1t = (short*)(ws + 62914560);     // 1 MB
    short* Wk1t = (short*)(ws + 63963136);     // 1 MB
    short* Wq2t = (short*)(ws + 65011712);     // 512 KB
    short* Wk2t = (short*)(ws + 65536000);     // 512 KB
    short* Wvt  = (short*)(ws + 66060288);     // 512 KB
    short* Wo3t = (short*)(ws + 66584576);     // 1.5 MB -> end 68,157,440

    dim3 blk(256);
    // 1/sqrt(32) * log2(e)  (exp2-based softmax)
    const float qscale = 0.17677669529663687f * 1.4426950408889634f;

    // weight prep
    wcast_t<<<dim3(32, 16), blk, 0, stream>>>(Wq1, Wq1t, 512, 1024);
    wcast_t<<<dim3(32, 16), blk, 0, stream>>>(Wk1, Wk1t, 512, 1024);
    wcast_t<<<dim3(8, 32), blk, 0, stream>>>(Wq2, Wq2t, 1024, 256);
    wcast_t<<<dim3(8, 32), blk, 0, stream>>>(Wk2, Wk2t, 1024, 256);
    wcast_t<<<dim3(16, 16), blk, 0, stream>>>(Wv, Wvt, 512, 512);
    wcast_t3<<<dim3(16, 16), blk, 0, stream>>>(Wo, Wo3t, 512, 512);

    // MLP layer 1 (q & k batched): f32 A, GELU, bf16 out. N=1024, K=512
    gemm_bt<1, 1, 0><<<dim3(8, 64, 2), blk, 0, stream>>>(
        query, key, Wq1t, Wk1t, bq1, bk1, H1q, H1k, 1.f, 1.f, 1024, 512);
    // MLP layer 2 (q & k batched): q pre-scaled by qscale. N=256, K=1024
    gemm_bt<0, 0, 0><<<dim3(2, 64, 2), blk, 0, stream>>>(
        H1q, H1k, Wq2t, Wk2t, bq2, bk2, qbb, kbb, qscale, 1.f, 256, 1024);
    // v projection, plain bf16 (f32 A cast in staging). N=512, K=512
    gemm_bt<1, 0, 0><<<dim3(4, 64, 1), blk, 0, stream>>>(
        value, value, Wvt, Wvt, bv, bv, vbb, vbb, 1.f, 1.f, 512, 512);
    // frag-major repacks for flash
    repack_k<<<dim3(64, 16), blk, 0, stream>>>(kbb, kfr);
    repack_v<<<dim3(64, 16), blk, 0, stream>>>(vbb, vfr);
    // attention (writes split xb3 directly)
    flash_mfma32<<<dim3(64, 16), blk, 0, stream>>>(qbb, kfr, vfr, xb3);
    // output projection, split-bf16 (K=1536) -> f32
    gemm_bt<0, 0, 1><<<dim3(4, 64, 1), blk, 0, stream>>>(
        xb3, xb3, Wo3t, Wo3t, bo, bo, out, out, 1.f, 1.f, 512, 1536);
}

// Round 7
// 362.815 us; speedup vs baseline: 1.3228x; 1.3228x over previous
//
#include <hip/hip_runtime.h>
#include <math.h>

typedef __attribute__((ext_vector_type(8))) short short8;
typedef __bf16 bf16x8 __attribute__((ext_vector_type(8)));
typedef __attribute__((ext_vector_type(4))) float f32x4;
typedef __attribute__((ext_vector_type(16))) float f32x16;

__device__ inline short f2bf(float f) {
    unsigned u = __builtin_bit_cast(unsigned, f);
    u += 0x7fff + ((u >> 16) & 1);   // round-to-nearest-even
    return (short)(u >> 16);
}
__device__ inline float bf2f(short h) {
    return __builtin_bit_cast(float, ((unsigned)(unsigned short)h) << 16);
}
__device__ inline float gelu_f(float x) {
    return 0.5f * x * (1.f + erff(x * 0.70710678118654752f));
}

// ---------------------------------------------------------------------------
// W f32 [K][N] -> Wt bf16 [N][K]
// ---------------------------------------------------------------------------
__global__ __launch_bounds__(256) void wcast_t(
    const float* __restrict__ W, short* __restrict__ Wt, int K, int N)
{
    __shared__ float T[32][33];
    int k0 = blockIdx.y * 32, n0 = blockIdx.x * 32;
    int tid = threadIdx.x;
    int r = tid >> 3, c4 = (tid & 7) * 4;
    float4 v = *(const float4*)&W[(size_t)(k0 + r) * N + n0 + c4];
    T[r][c4 + 0] = v.x; T[r][c4 + 1] = v.y; T[r][c4 + 2] = v.z; T[r][c4 + 3] = v.w;
    __syncthreads();
    short4 o;
    o.x = f2bf(T[c4 + 0][r]);
    o.y = f2bf(T[c4 + 1][r]);
    o.z = f2bf(T[c4 + 2][r]);
    o.w = f2bf(T[c4 + 3][r]);
    *(short4*)&Wt[(size_t)(n0 + r) * K + k0 + c4] = o;
}

// W f32 [K][N] -> W3t bf16 [N][3K] = [hi | lo | hi]
__global__ __launch_bounds__(256) void wcast_t3(
    const float* __restrict__ W, short* __restrict__ W3t, int K, int N)
{
    __shared__ float T[32][33];
    int k0 = blockIdx.y * 32, n0 = blockIdx.x * 32;
    int tid = threadIdx.x;
    int r = tid >> 3, c4 = (tid & 7) * 4;
    float4 v = *(const float4*)&W[(size_t)(k0 + r) * N + n0 + c4];
    T[r][c4 + 0] = v.x; T[r][c4 + 1] = v.y; T[r][c4 + 2] = v.z; T[r][c4 + 3] = v.w;
    __syncthreads();
    short4 hi, lo;
    float f;
    f = T[c4 + 0][r]; hi.x = f2bf(f); lo.x = f2bf(f - bf2f(hi.x));
    f = T[c4 + 1][r]; hi.y = f2bf(f); lo.y = f2bf(f - bf2f(hi.y));
    f = T[c4 + 2][r]; hi.z = f2bf(f); lo.z = f2bf(f - bf2f(hi.z));
    f = T[c4 + 3][r]; hi.w = f2bf(f); lo.w = f2bf(f - bf2f(hi.w));
    short* d = W3t + (size_t)(n0 + r) * 3 * K + k0 + c4;
    *(short4*)d = hi;
    *(short4*)(d + K) = lo;
    *(short4*)(d + 2 * K) = hi;
}

// ---------------------------------------------------------------------------
// bf16 MFMA GEMM, B^T layout (proven R4).
// ---------------------------------------------------------------------------
template <int AF32, int ACT, int OUTF32>
__global__ __launch_bounds__(256) void gemm_bt(
    const void* A0_, const void* A1_,
    const short* __restrict__ B0, const short* __restrict__ B1,
    const float* __restrict__ b0, const float* __restrict__ b1,
    void* C0_, void* C1_,
    float s0, float s1, int N, int K)
{
    const int z = blockIdx.z;
    const void* A_ = z ? A1_ : A0_;
    const short* B = z ? B1 : B0;
    const float* bias = z ? b1 : b0;
    void* C_ = z ? C1_ : C0_;
    const float scale = z ? s1 : s0;

    const int bm = blockIdx.y * 128;
    const int bn = blockIdx.x * 128;
    const int tid = threadIdx.x;
    const int w = tid >> 6;
    const int lane = tid & 63;
    const int l15 = lane & 15, quad = lane >> 4;
    const int wm = (w >> 1) * 64, wn = (w & 1) * 64;

    __shared__ __align__(16) short As[128 * 32];
    __shared__ __align__(16) short Bs[128 * 32];

    f32x4 acc[4][4];
#pragma unroll
    for (int mt = 0; mt < 4; ++mt)
#pragma unroll
        for (int nt = 0; nt < 4; ++nt) acc[mt][nt] = (f32x4){0.f, 0.f, 0.f, 0.f};

    const int ga0 = tid * 2;

    for (int k0 = 0; k0 < K; k0 += 32) {
#pragma unroll
        for (int i = 0; i < 2; ++i) {
            int ga = ga0 + i;
            int row = ga >> 2, g = ga & 3;
            short8 aval;
            if (AF32) {
                const float* ap = (const float*)A_ + (size_t)(bm + row) * K + k0 + g * 8;
                float4 f0 = *(const float4*)ap;
                float4 f1 = *(const float4*)(ap + 4);
                aval[0] = f2bf(f0.x); aval[1] = f2bf(f0.y);
                aval[2] = f2bf(f0.z); aval[3] = f2bf(f0.w);
                aval[4] = f2bf(f1.x); aval[5] = f2bf(f1.y);
                aval[6] = f2bf(f1.z); aval[7] = f2bf(f1.w);
            } else {
                aval = *(const short8*)((const short*)A_ + (size_t)(bm + row) * K + k0 + g * 8);
            }
            *(short8*)(void*)&As[row * 32 + ((g ^ (row & 3)) * 8)] = aval;
            short8 bval = *(const short8*)(const void*)&B[(size_t)(bn + row) * K + k0 + g * 8];
            *(short8*)(void*)&Bs[row * 32 + ((g ^ (row & 3)) * 8)] = bval;
        }
        __syncthreads();

        bf16x8 af[4], bfr[4];
#pragma unroll
        for (int t = 0; t < 4; ++t) {
            af[t] = __builtin_bit_cast(bf16x8,
                *(const short8*)(const void*)&As[(wm + t * 16 + l15) * 32 + ((quad ^ (l15 & 3)) * 8)]);
            bfr[t] = __builtin_bit_cast(bf16x8,
                *(const short8*)(const void*)&Bs[(wn + t * 16 + l15) * 32 + ((quad ^ (l15 & 3)) * 8)]);
        }
#pragma unroll
        for (int mt = 0; mt < 4; ++mt)
#pragma unroll
            for (int nt = 0; nt < 4; ++nt)
                acc[mt][nt] = __builtin_amdgcn_mfma_f32_16x16x32_bf16(af[mt], bfr[nt], acc[mt][nt], 0, 0, 0);
        __syncthreads();
    }

    float bv[4];
#pragma unroll
    for (int nt = 0; nt < 4; ++nt) bv[nt] = bias[bn + wn + nt * 16 + l15];
#pragma unroll
    for (int mt = 0; mt < 4; ++mt)
#pragma unroll
        for (int r = 0; r < 4; ++r) {
            int row = bm + wm + mt * 16 + quad * 4 + r;
#pragma unroll
            for (int nt = 0; nt < 4; ++nt) {
                float v = acc[mt][nt][r] + bv[nt];
                if (ACT) v = gelu_f(v);
                v *= scale;
                int col = bn + wn + nt * 16 + l15;
                if (OUTF32) ((float*)C_)[(size_t)row * N + col] = v;
                else        ((short*)C_)[(size_t)row * N + col] = f2bf(v);
            }
        }
}

// ---------------------------------------------------------------------------
// K repack: kbb bf16 [8192][256] -> kfr frag-major (proven R5)
// chunk c = nt*2+ks: key = kt*64 + nt*32 + (l&31), k = ks*16 + (l>>5)*8 + j
// ---------------------------------------------------------------------------
__global__ __launch_bounds__(256) void repack_k(
    const short* __restrict__ kb, short* __restrict__ kfr)
{
    const int kt = blockIdx.x, bh = blockIdx.y;
    const int b = bh >> 3, h = bh & 7;
    const int t = threadIdx.x;
    const int c = t >> 6, l = t & 63;
    const int nt = c >> 1, ks = c & 1;
    int key = kt * 64 + nt * 32 + (l & 31);
    int k = ks * 16 + (l >> 5) * 8;
    short8 v = *(const short8*)(const void*)&kb[(size_t)(b * 4096 + key) * 256 + h * 32 + k];
    *(short8*)(void*)&kfr[((((size_t)bh * 64 + kt) * 4 + c) * 64 + l) * 8] = v;
}

// ---------------------------------------------------------------------------
// V repack: vbb bf16 [8192][512] -> vfr frag-major (proven R5)
// chunk = dt*4+ks: dk = dt*32 + (l&31), key = ks*16 + (l>>5)*8 + j
// ---------------------------------------------------------------------------
__global__ __launch_bounds__(256) void repack_v(
    const short* __restrict__ vbb, short* __restrict__ vfr)
{
    const int kt = blockIdx.x, bh = blockIdx.y;
    const int b = bh >> 3, h = bh & 7;
    const int t = threadIdx.x;
    __shared__ short Vt[64][72];   // [key][dk]

#pragma unroll
    for (int it = 0; it < 2; ++it) {
        int idx = t + it * 256;
        int keyr = idx >> 3, c8 = (idx & 7) * 8;
        *(short8*)(void*)&Vt[keyr][c8] =
            *(const short8*)(const void*)&vbb[(size_t)(b * 4096 + kt * 64 + keyr) * 512 + h * 64 + c8];
    }
    __syncthreads();
#pragma unroll
    for (int it = 0; it < 2; ++it) {
        int chunk = (t >> 6) * 2 + it;
        int l = t & 63;
        int dt = chunk >> 2, ks = chunk & 3;
        short8 o;
#pragma unroll
        for (int j = 0; j < 8; ++j)
            o[j] = Vt[ks * 16 + (l >> 5) * 8 + j][dt * 32 + (l & 31)];
        *(short8*)(void*)&vfr[((((size_t)bh * 64 + kt) * 8 + chunk) * 64 + l) * 8] = o;
    }
}

// ---------------------------------------------------------------------------
// Barrier-free flash attention. Block = 128 threads = 2 waves.
// Wave wv handles 32 q rows x keys [wv*2048, wv*2048+2048); fully independent
// (K/V frags loaded DIRECTLY from global frag-major buffers; LDS only for the
// wave-private P round-trip). No-max softmax (scores bounded) via v_exp2.
// Operand-swapped QK^T (A=K, B=Q -> S^T) so P-writes are 8x ds_write_b64.
// One __syncthreads total: the final key-half combine (add O, l partials).
// ---------------------------------------------------------------------------
__global__ __launch_bounds__(128, 4) void flash_ks(
    const short* __restrict__ qb, const short* __restrict__ kfr,
    const short* __restrict__ vfr, short* __restrict__ xb3)
{
    const int qt = blockIdx.x;   // 0..127: 32 q rows each
    const int bh = blockIdx.y;   // 0..15
    const int b = bh >> 3, h = bh & 7;
    const int wv = threadIdx.x >> 6;   // key-split 0/1
    const int lane = threadIdx.x & 63;
    const int l31 = lane & 31;
    const int half = lane >> 5;

    __shared__ __align__(16) short Pbuf[2][32 * 72];  // per-wave P [32 q][64 key], stride 72
    __shared__ float redO[32][66];                    // combine: [q][64 dk + pad]
    __shared__ float redl[2][32];                     // combine: per-wave l[q]

    short* Pw = Pbuf[wv];

    // Q as B-operand: lane n=q=l31, k = half*8+j (frag0: k 0..15, frag1: 16..31)
    const short* qrow = qb + (size_t)(b * 4096 + qt * 32 + l31) * 256 + h * 32 + half * 8;
    bf16x8 qf0 = __builtin_bit_cast(bf16x8, *(const short8*)(const void*)qrow);
    bf16x8 qf1 = __builtin_bit_cast(bf16x8, *(const short8*)(const void*)(qrow + 16));

    f32x16 O0{}, O1{};
    float la = 0.f;

    const short* kbase = kfr + ((size_t)bh * 64) * 4 * 512 + lane * 8;
    const short* vbase = vfr + ((size_t)bh * 64) * 8 * 512 + lane * 8;

#pragma unroll 1
    for (int t = 0; t < 32; ++t) {
        const int kt = wv * 32 + t;
        // direct frag loads from global (coalesced 16B/lane, no LDS, no barrier)
        bf16x8 kc[4], vc[8];
        const short* kp = kbase + (size_t)kt * 4 * 512;
        const short* vp = vbase + (size_t)kt * 8 * 512;
#pragma unroll
        for (int c = 0; c < 4; ++c)
            kc[c] = __builtin_bit_cast(bf16x8, *(const short8*)(const void*)(kp + c * 512));
#pragma unroll
        for (int c = 0; c < 8; ++c)
            vc[c] = __builtin_bit_cast(bf16x8, *(const short8*)(const void*)(vp + c * 512));

        // S^T[64 key][32 q]: A=K, B=Q. C col = q = l31, rows = keys.
        f32x16 zero{};
        f32x16 s0 = __builtin_amdgcn_mfma_f32_32x32x16_bf16(kc[0], qf0, zero, 0, 0, 0);
        s0 = __builtin_amdgcn_mfma_f32_32x32x16_bf16(kc[1], qf1, s0, 0, 0, 0);
        f32x16 s1 = __builtin_amdgcn_mfma_f32_32x32x16_bf16(kc[2], qf0, zero, 0, 0, 0);
        s1 = __builtin_amdgcn_mfma_f32_32x32x16_bf16(kc[3], qf1, s1, 0, 0, 0);

        // exp + l accumulate + P -> LDS as b64 packs of 4 consecutive keys
        // C row map: key_within_32 = (r&3) + 8*(r>>2) + 4*half
#pragma unroll
        for (int nt = 0; nt < 2; ++nt) {
            const f32x16& s = nt ? s1 : s0;
#pragma unroll
            for (int r2 = 0; r2 < 4; ++r2) {
                short4 pk;
                float p0 = __builtin_amdgcn_exp2f(s[r2 * 4 + 0]);
                float p1 = __builtin_amdgcn_exp2f(s[r2 * 4 + 1]);
                float p2 = __builtin_amdgcn_exp2f(s[r2 * 4 + 2]);
                float p3 = __builtin_amdgcn_exp2f(s[r2 * 4 + 3]);
                la += (p0 + p1) + (p2 + p3);
                pk.x = f2bf(p0); pk.y = f2bf(p1); pk.z = f2bf(p2); pk.w = f2bf(p3);
                *(short4*)(void*)&Pw[l31 * 72 + nt * 32 + r2 * 8 + half * 4] = pk;
            }
        }

        // PV: A = P[m=q l31][k=key], B = V^T chunks. O cols = dk.
        bf16x8 pf[4];
#pragma unroll
        for (int ks = 0; ks < 4; ++ks)
            pf[ks] = __builtin_bit_cast(bf16x8,
                *(const short8*)(const void*)&Pw[l31 * 72 + ks * 16 + half * 8]);
#pragma unroll
        for (int ks = 0; ks < 4; ++ks) {
            O0 = __builtin_amdgcn_mfma_f32_32x32x16_bf16(pf[ks], vc[ks], O0, 0, 0, 0);
            O1 = __builtin_amdgcn_mfma_f32_32x32x16_bf16(pf[ks], vc[4 + ks], O1, 0, 0, 0);
        }
    }

    // la currently: sum over this lane's 32-of-64 keys per tile; lane l and
    // l+32 together cover all -> one xor-32 shuffle gives l[q=l31] for this wave.
    la += __shfl_xor(la, 32);

    // ---- combine the two key-halves ----
    if (half == 0) redl[wv][l31] = la;
    if (wv == 1) {
#pragma unroll
        for (int r = 0; r < 16; ++r) {
            int q = (r & 3) + 8 * (r >> 2) + 4 * half;
            redO[q][l31] = O0[r];
            redO[q][32 + l31] = O1[r];
        }
    }
    __syncthreads();
    if (wv == 0) {
#pragma unroll
        for (int r = 0; r < 16; ++r) {
            int q = (r & 3) + 8 * (r >> 2) + 4 * half;
            float o0 = O0[r] + redO[q][l31];
            float o1 = O1[r] + redO[q][32 + l31];
            float inv = 1.f / (redl[0][q] + redl[1][q]);
            float x0 = o0 * inv, x1 = o1 * inv;
            short hi0 = f2bf(x0), hi1 = f2bf(x1);
            short lo0 = f2bf(x0 - bf2f(hi0)), lo1 = f2bf(x1 - bf2f(hi1));
            size_t row = (size_t)(b * 4096 + qt * 32 + q);
            short* d = xb3 + row * 1536 + h * 64 + l31;
            d[0] = hi0;    d[32] = hi1;
            d[512] = hi0;  d[544] = hi1;
            d[1024] = lo0; d[1056] = lo1;
        }
    }
}

// ---------------------------------------------------------------------------
extern "C" void kernel_launch(void* const* d_in, const int* in_sizes, int n_in,
                              void* d_out, int out_size, void* d_ws, size_t ws_size,
                              hipStream_t stream)
{
    const float* query = (const float*)d_in[0];
    const float* key   = (const float*)d_in[1];
    const float* value = (const float*)d_in[2];
    const float* Wq1   = (const float*)d_in[3];
    const float* bq1   = (const float*)d_in[4];
    const float* Wq2   = (const float*)d_in[5];
    const float* bq2   = (const float*)d_in[6];
    const float* Wk1   = (const float*)d_in[7];
    const float* bk1   = (const float*)d_in[8];
    const float* Wk2   = (const float*)d_in[9];
    const float* bk2   = (const float*)d_in[10];
    const float* Wv    = (const float*)d_in[11];
    const float* bv    = (const float*)d_in[12];
    const float* Wo    = (const float*)d_in[13];
    const float* bo    = (const float*)d_in[14];
    float* out = (float*)d_out;

    // Workspace (bytes), total 68 MB:
    char* ws = (char*)d_ws;
    short* H1q  = (short*)(ws + 0);            // 16 MB   (dead after mlp2)
    short* H1k  = (short*)(ws + 16777216);     // 16 MB   (dead after mlp2)
    short* xb3  = (short*)(ws + 0);            // 25,165,824 (overlays H1)
    short* qbb  = (short*)(ws + 33554432);     // 4 MB
    short* kbb  = (short*)(ws + 37748736);     // 4 MB
    short* vbb  = (short*)(ws + 41943040);     // 8 MB
    short* kfr  = (short*)(ws + 50331648);     // 4 MB
    short* vfr  = (short*)(ws + 54525952);     // 8 MB
    short* Wq1t = (short*)(ws + 62914560);     // 1 MB
    short* Wk1t = (short*)(ws + 63963136);     // 1 MB
    short* Wq2t = (short*)(ws + 65011712);     // 512 KB
    short* Wk2t = (short*)(ws + 65536000);     // 512 KB
    short* Wvt  = (short*)(ws + 66060288);     // 512 KB
    short* Wo3t = (short*)(ws + 66584576);     // 1.5 MB -> end 68,157,440

    dim3 blk(256);
    // 1/sqrt(32) * log2(e)  (exp2-based softmax)
    const float qscale = 0.17677669529663687f * 1.4426950408889634f;

    // weight prep
    wcast_t<<<dim3(32, 16), blk, 0, stream>>>(Wq1, Wq1t, 512, 1024);
    wcast_t<<<dim3(32, 16), blk, 0, stream>>>(Wk1, Wk1t, 512, 1024);
    wcast_t<<<dim3(8, 32), blk, 0, stream>>>(Wq2, Wq2t, 1024, 256);
    wcast_t<<<dim3(8, 32), blk, 0, stream>>>(Wk2, Wk2t, 1024, 256);
    wcast_t<<<dim3(16, 16), blk, 0, stream>>>(Wv, Wvt, 512, 512);
    wcast_t3<<<dim3(16, 16), blk, 0, stream>>>(Wo, Wo3t, 512, 512);

    // MLP layer 1 (q & k batched): f32 A, GELU, bf16 out. N=1024, K=512
    gemm_bt<1, 1, 0><<<dim3(8, 64, 2), blk, 0, stream>>>(
        query, key, Wq1t, Wk1t, bq1, bk1, H1q, H1k, 1.f, 1.f, 1024, 512);
    // MLP layer 2 (q & k batched): q pre-scaled by qscale. N=256, K=1024
    gemm_bt<0, 0, 0><<<dim3(2, 64, 2), blk, 0, stream>>>(
        H1q, H1k, Wq2t, Wk2t, bq2, bk2, qbb, kbb, qscale, 1.f, 256, 1024);
    // v projection, plain bf16 (f32 A cast in staging). N=512, K=512
    gemm_bt<1, 0, 0><<<dim3(4, 64, 1), blk, 0, stream>>>(
        value, value, Wvt, Wvt, bv, bv, vbb, vbb, 1.f, 1.f, 512, 512);
    // frag-major repacks for flash
    repack_k<<<dim3(64, 16), blk, 0, stream>>>(kbb, kfr);
    repack_v<<<dim3(64, 16), blk, 0, stream>>>(vbb, vfr);
    // attention: barrier-free, 2-wave blocks, key-split in-block
    flash_ks<<<dim3(128, 16), dim3(128), 0, stream>>>(qbb, kfr, vfr, xb3);
    // output projection, split-bf16 (K=1536) -> f32
    gemm_bt<0, 0, 1><<<dim3(4, 64, 1), blk, 0, stream>>>(
        xb3, xb3, Wo3t, Wo3t, bo, bo, out, out, 1.f, 1.f, 512, 1536);
}

// Round 8
// 344.345 us; speedup vs baseline: 1.3938x; 1.0536x over previous
//
#include <hip/hip_runtime.h>
#include <math.h>

typedef __attribute__((ext_vector_type(8))) short short8;
typedef __bf16 bf16x8 __attribute__((ext_vector_type(8)));
typedef __attribute__((ext_vector_type(4))) float f32x4;
typedef __attribute__((ext_vector_type(16))) float f32x16;

__device__ inline short f2bf(float f) {
    unsigned u = __builtin_bit_cast(unsigned, f);
    u += 0x7fff + ((u >> 16) & 1);   // round-to-nearest-even
    return (short)(u >> 16);
}
__device__ inline float bf2f(short h) {
    return __builtin_bit_cast(float, ((unsigned)(unsigned short)h) << 16);
}
__device__ inline float gelu_f(float x) {
    return 0.5f * x * (1.f + erff(x * 0.70710678118654752f));
}

// ---------------------------------------------------------------------------
// Cast query/key/value f32 -> bf16 (blockIdx.y selects tensor)
// ---------------------------------------------------------------------------
__global__ __launch_bounds__(256) void cast3(
    const float* __restrict__ q, const float* __restrict__ k,
    const float* __restrict__ v,
    short* __restrict__ qc, short* __restrict__ kc, short* __restrict__ vc)
{
    const float* src = blockIdx.y == 0 ? q : (blockIdx.y == 1 ? k : v);
    short* dst = blockIdx.y == 0 ? qc : (blockIdx.y == 1 ? kc : vc);
    size_t i = ((size_t)blockIdx.x * 256 + threadIdx.x) * 8;
    float4 a = *(const float4*)(src + i);
    float4 b = *(const float4*)(src + i + 4);
    short8 o;
    o[0] = f2bf(a.x); o[1] = f2bf(a.y); o[2] = f2bf(a.z); o[3] = f2bf(a.w);
    o[4] = f2bf(b.x); o[5] = f2bf(b.y); o[6] = f2bf(b.z); o[7] = f2bf(b.w);
    *(short8*)(void*)(dst + i) = o;
}

// ---------------------------------------------------------------------------
// W f32 [K][N] -> Wt bf16 [N][K]
// ---------------------------------------------------------------------------
__global__ __launch_bounds__(256) void wcast_t(
    const float* __restrict__ W, short* __restrict__ Wt, int K, int N)
{
    __shared__ float T[32][33];
    int k0 = blockIdx.y * 32, n0 = blockIdx.x * 32;
    int tid = threadIdx.x;
    int r = tid >> 3, c4 = (tid & 7) * 4;
    float4 v = *(const float4*)&W[(size_t)(k0 + r) * N + n0 + c4];
    T[r][c4 + 0] = v.x; T[r][c4 + 1] = v.y; T[r][c4 + 2] = v.z; T[r][c4 + 3] = v.w;
    __syncthreads();
    short4 o;
    o.x = f2bf(T[c4 + 0][r]);
    o.y = f2bf(T[c4 + 1][r]);
    o.z = f2bf(T[c4 + 2][r]);
    o.w = f2bf(T[c4 + 3][r]);
    *(short4*)&Wt[(size_t)(n0 + r) * K + k0 + c4] = o;
}

// W f32 [K][N] -> W3t bf16 [N][3K] = [hi | lo | hi]
__global__ __launch_bounds__(256) void wcast_t3(
    const float* __restrict__ W, short* __restrict__ W3t, int K, int N)
{
    __shared__ float T[32][33];
    int k0 = blockIdx.y * 32, n0 = blockIdx.x * 32;
    int tid = threadIdx.x;
    int r = tid >> 3, c4 = (tid & 7) * 4;
    float4 v = *(const float4*)&W[(size_t)(k0 + r) * N + n0 + c4];
    T[r][c4 + 0] = v.x; T[r][c4 + 1] = v.y; T[r][c4 + 2] = v.z; T[r][c4 + 3] = v.w;
    __syncthreads();
    short4 hi, lo;
    float f;
    f = T[c4 + 0][r]; hi.x = f2bf(f); lo.x = f2bf(f - bf2f(hi.x));
    f = T[c4 + 1][r]; hi.y = f2bf(f); lo.y = f2bf(f - bf2f(hi.y));
    f = T[c4 + 2][r]; hi.z = f2bf(f); lo.z = f2bf(f - bf2f(hi.z));
    f = T[c4 + 3][r]; hi.w = f2bf(f); lo.w = f2bf(f - bf2f(hi.w));
    short* d = W3t + (size_t)(n0 + r) * 3 * K + k0 + c4;
    *(short4*)d = hi;
    *(short4*)(d + K) = lo;
    *(short4*)(d + 2 * K) = hi;
}

// ---------------------------------------------------------------------------
// bf16 MFMA GEMM, B^T layout, XCD-aware block swizzle.
// Grid x = nbn*64 flat; xcd = L&7, bn = (L>>3)%nbn, bm = ((L>>3)/nbn)*8+xcd
// so all bn-blocks of one A-panel land on one XCD (L2 fetch-once heuristic).
// ---------------------------------------------------------------------------
template <int ACT, int OUTF32>
__global__ __launch_bounds__(256) void gemm_bt(
    const short* __restrict__ A0, const short* __restrict__ A1,
    const short* __restrict__ B0, const short* __restrict__ B1,
    const float* __restrict__ b0, const float* __restrict__ b1,
    void* C0_, void* C1_,
    float s0, float s1, int nbn, int N, int K)
{
    const int z = blockIdx.z;
    const short* A = z ? A1 : A0;
    const short* B = z ? B1 : B0;
    const float* bias = z ? b1 : b0;
    void* C_ = z ? C1_ : C0_;
    const float scale = z ? s1 : s0;

    const int L = blockIdx.x;
    const int xcd = L & 7;
    const int per = L >> 3;
    const int bn = (per % nbn) * 128;
    const int bm = ((per / nbn) * 8 + xcd) * 128;

    const int tid = threadIdx.x;
    const int w = tid >> 6;
    const int lane = tid & 63;
    const int l15 = lane & 15, quad = lane >> 4;
    const int wm = (w >> 1) * 64, wn = (w & 1) * 64;

    __shared__ __align__(16) short As[128 * 32];
    __shared__ __align__(16) short Bs[128 * 32];

    f32x4 acc[4][4];
#pragma unroll
    for (int mt = 0; mt < 4; ++mt)
#pragma unroll
        for (int nt = 0; nt < 4; ++nt) acc[mt][nt] = (f32x4){0.f, 0.f, 0.f, 0.f};

    const int ga0 = tid * 2;

    for (int k0 = 0; k0 < K; k0 += 32) {
#pragma unroll
        for (int i = 0; i < 2; ++i) {
            int ga = ga0 + i;
            int row = ga >> 2, g = ga & 3;
            short8 aval = *(const short8*)(const void*)&A[(size_t)(bm + row) * K + k0 + g * 8];
            *(short8*)(void*)&As[row * 32 + ((g ^ (row & 3)) * 8)] = aval;
            short8 bval = *(const short8*)(const void*)&B[(size_t)(bn + row) * K + k0 + g * 8];
            *(short8*)(void*)&Bs[row * 32 + ((g ^ (row & 3)) * 8)] = bval;
        }
        __syncthreads();

        bf16x8 af[4], bfr[4];
#pragma unroll
        for (int t = 0; t < 4; ++t) {
            af[t] = __builtin_bit_cast(bf16x8,
                *(const short8*)(const void*)&As[(wm + t * 16 + l15) * 32 + ((quad ^ (l15 & 3)) * 8)]);
            bfr[t] = __builtin_bit_cast(bf16x8,
                *(const short8*)(const void*)&Bs[(wn + t * 16 + l15) * 32 + ((quad ^ (l15 & 3)) * 8)]);
        }
#pragma unroll
        for (int mt = 0; mt < 4; ++mt)
#pragma unroll
            for (int nt = 0; nt < 4; ++nt)
                acc[mt][nt] = __builtin_amdgcn_mfma_f32_16x16x32_bf16(af[mt], bfr[nt], acc[mt][nt], 0, 0, 0);
        __syncthreads();
    }

    float bv[4];
#pragma unroll
    for (int nt = 0; nt < 4; ++nt) bv[nt] = bias[bn + wn + nt * 16 + l15];
#pragma unroll
    for (int mt = 0; mt < 4; ++mt)
#pragma unroll
        for (int r = 0; r < 4; ++r) {
            int row = bm + wm + mt * 16 + quad * 4 + r;
#pragma unroll
            for (int nt = 0; nt < 4; ++nt) {
                float v = acc[mt][nt][r] + bv[nt];
                if (ACT) v = gelu_f(v);
                v *= scale;
                int col = bn + wn + nt * 16 + l15;
                if (OUTF32) ((float*)C_)[(size_t)row * N + col] = v;
                else        ((short*)C_)[(size_t)row * N + col] = f2bf(v);
            }
        }
}

// ---------------------------------------------------------------------------
// K repack: kbb bf16 [8192][256] -> kfr frag-major (proven R5)
// ---------------------------------------------------------------------------
__global__ __launch_bounds__(256) void repack_k(
    const short* __restrict__ kb, short* __restrict__ kfr)
{
    const int kt = blockIdx.x, bh = blockIdx.y;
    const int b = bh >> 3, h = bh & 7;
    const int t = threadIdx.x;
    const int c = t >> 6, l = t & 63;
    const int nt = c >> 1, ks = c & 1;
    int key = kt * 64 + nt * 32 + (l & 31);
    int k = ks * 16 + (l >> 5) * 8;
    short8 v = *(const short8*)(const void*)&kb[(size_t)(b * 4096 + key) * 256 + h * 32 + k];
    *(short8*)(void*)&kfr[((((size_t)bh * 64 + kt) * 4 + c) * 64 + l) * 8] = v;
}

// ---------------------------------------------------------------------------
// V repack: vbb bf16 [8192][512] -> vfr frag-major (proven R5)
// ---------------------------------------------------------------------------
__global__ __launch_bounds__(256) void repack_v(
    const short* __restrict__ vbb, short* __restrict__ vfr)
{
    const int kt = blockIdx.x, bh = blockIdx.y;
    const int b = bh >> 3, h = bh & 7;
    const int t = threadIdx.x;
    __shared__ short Vt[64][72];   // [key][dk]

#pragma unroll
    for (int it = 0; it < 2; ++it) {
        int idx = t + it * 256;
        int keyr = idx >> 3, c8 = (idx & 7) * 8;
        *(short8*)(void*)&Vt[keyr][c8] =
            *(const short8*)(const void*)&vbb[(size_t)(b * 4096 + kt * 64 + keyr) * 512 + h * 64 + c8];
    }
    __syncthreads();
#pragma unroll
    for (int it = 0; it < 2; ++it) {
        int chunk = (t >> 6) * 2 + it;
        int l = t & 63;
        int dt = chunk >> 2, ks = chunk & 3;
        short8 o;
#pragma unroll
        for (int j = 0; j < 8; ++j)
            o[j] = Vt[ks * 16 + (l >> 5) * 8 + j][dt * 32 + (l & 31)];
        *(short8*)(void*)&vfr[((((size_t)bh * 64 + kt) * 8 + chunk) * 64 + l) * 8] = o;
    }
}

// ---------------------------------------------------------------------------
// Barrier-free flash attention (proven R7). Block = 128 threads = 2 waves,
// key-split; direct frag-major global loads; one final combine barrier.
// ---------------------------------------------------------------------------
__global__ __launch_bounds__(128, 4) void flash_ks(
    const short* __restrict__ qb, const short* __restrict__ kfr,
    const short* __restrict__ vfr, short* __restrict__ xb3)
{
    const int qt = blockIdx.x;   // 0..127: 32 q rows each
    const int bh = blockIdx.y;   // 0..15
    const int b = bh >> 3, h = bh & 7;
    const int wv = threadIdx.x >> 6;   // key-split 0/1
    const int lane = threadIdx.x & 63;
    const int l31 = lane & 31;
    const int half = lane >> 5;

    __shared__ __align__(16) short Pbuf[2][32 * 72];
    __shared__ float redO[32][66];
    __shared__ float redl[2][32];

    short* Pw = Pbuf[wv];

    const short* qrow = qb + (size_t)(b * 4096 + qt * 32 + l31) * 256 + h * 32 + half * 8;
    bf16x8 qf0 = __builtin_bit_cast(bf16x8, *(const short8*)(const void*)qrow);
    bf16x8 qf1 = __builtin_bit_cast(bf16x8, *(const short8*)(const void*)(qrow + 16));

    f32x16 O0{}, O1{};
    float la = 0.f;

    const short* kbase = kfr + ((size_t)bh * 64) * 4 * 512 + lane * 8;
    const short* vbase = vfr + ((size_t)bh * 64) * 8 * 512 + lane * 8;

#pragma unroll 1
    for (int t = 0; t < 32; ++t) {
        const int kt = wv * 32 + t;
        bf16x8 kc[4], vc[8];
        const short* kp = kbase + (size_t)kt * 4 * 512;
        const short* vp = vbase + (size_t)kt * 8 * 512;
#pragma unroll
        for (int c = 0; c < 4; ++c)
            kc[c] = __builtin_bit_cast(bf16x8, *(const short8*)(const void*)(kp + c * 512));
#pragma unroll
        for (int c = 0; c < 8; ++c)
            vc[c] = __builtin_bit_cast(bf16x8, *(const short8*)(const void*)(vp + c * 512));

        f32x16 zero{};
        f32x16 s0 = __builtin_amdgcn_mfma_f32_32x32x16_bf16(kc[0], qf0, zero, 0, 0, 0);
        s0 = __builtin_amdgcn_mfma_f32_32x32x16_bf16(kc[1], qf1, s0, 0, 0, 0);
        f32x16 s1 = __builtin_amdgcn_mfma_f32_32x32x16_bf16(kc[2], qf0, zero, 0, 0, 0);
        s1 = __builtin_amdgcn_mfma_f32_32x32x16_bf16(kc[3], qf1, s1, 0, 0, 0);

#pragma unroll
        for (int nt = 0; nt < 2; ++nt) {
            const f32x16& s = nt ? s1 : s0;
#pragma unroll
            for (int r2 = 0; r2 < 4; ++r2) {
                short4 pk;
                float p0 = __builtin_amdgcn_exp2f(s[r2 * 4 + 0]);
                float p1 = __builtin_amdgcn_exp2f(s[r2 * 4 + 1]);
                float p2 = __builtin_amdgcn_exp2f(s[r2 * 4 + 2]);
                float p3 = __builtin_amdgcn_exp2f(s[r2 * 4 + 3]);
                la += (p0 + p1) + (p2 + p3);
                pk.x = f2bf(p0); pk.y = f2bf(p1); pk.z = f2bf(p2); pk.w = f2bf(p3);
                *(short4*)(void*)&Pw[l31 * 72 + nt * 32 + r2 * 8 + half * 4] = pk;
            }
        }

        bf16x8 pf[4];
#pragma unroll
        for (int ks = 0; ks < 4; ++ks)
            pf[ks] = __builtin_bit_cast(bf16x8,
                *(const short8*)(const void*)&Pw[l31 * 72 + ks * 16 + half * 8]);
#pragma unroll
        for (int ks = 0; ks < 4; ++ks) {
            O0 = __builtin_amdgcn_mfma_f32_32x32x16_bf16(pf[ks], vc[ks], O0, 0, 0, 0);
            O1 = __builtin_amdgcn_mfma_f32_32x32x16_bf16(pf[ks], vc[4 + ks], O1, 0, 0, 0);
        }
    }

    la += __shfl_xor(la, 32);

    if (half == 0) redl[wv][l31] = la;
    if (wv == 1) {
#pragma unroll
        for (int r = 0; r < 16; ++r) {
            int q = (r & 3) + 8 * (r >> 2) + 4 * half;
            redO[q][l31] = O0[r];
            redO[q][32 + l31] = O1[r];
        }
    }
    __syncthreads();
    if (wv == 0) {
#pragma unroll
        for (int r = 0; r < 16; ++r) {
            int q = (r & 3) + 8 * (r >> 2) + 4 * half;
            float o0 = O0[r] + redO[q][l31];
            float o1 = O1[r] + redO[q][32 + l31];
            float inv = 1.f / (redl[0][q] + redl[1][q]);
            float x0 = o0 * inv, x1 = o1 * inv;
            short hi0 = f2bf(x0), hi1 = f2bf(x1);
            short lo0 = f2bf(x0 - bf2f(hi0)), lo1 = f2bf(x1 - bf2f(hi1));
            size_t row = (size_t)(b * 4096 + qt * 32 + q);
            short* d = xb3 + row * 1536 + h * 64 + l31;
            d[0] = hi0;    d[32] = hi1;
            d[512] = hi0;  d[544] = hi1;
            d[1024] = lo0; d[1056] = lo1;
        }
    }
}

// ---------------------------------------------------------------------------
extern "C" void kernel_launch(void* const* d_in, const int* in_sizes, int n_in,
                              void* d_out, int out_size, void* d_ws, size_t ws_size,
                              hipStream_t stream)
{
    const float* query = (const float*)d_in[0];
    const float* key   = (const float*)d_in[1];
    const float* value = (const float*)d_in[2];
    const float* Wq1   = (const float*)d_in[3];
    const float* bq1   = (const float*)d_in[4];
    const float* Wq2   = (const float*)d_in[5];
    const float* bq2   = (const float*)d_in[6];
    const float* Wk1   = (const float*)d_in[7];
    const float* bk1   = (const float*)d_in[8];
    const float* Wk2   = (const float*)d_in[9];
    const float* bk2   = (const float*)d_in[10];
    const float* Wv    = (const float*)d_in[11];
    const float* bv    = (const float*)d_in[12];
    const float* Wo    = (const float*)d_in[13];
    const float* bo    = (const float*)d_in[14];
    float* out = (float*)d_out;

    // Workspace (bytes), total 68 MB with overlays:
    //  0..32M  : H1q/H1k (live MLP1->MLP2); later xb3 0..24M (flash->outproj)
    // 32..40M  : qcast (live cast3->MLP1); later qbb(32-36)+kbb(36-40) (MLP2->)
    // 40..48M  : kcast (live cast3->MLP1); later vbb (vproj->repack_v)
    // 48..56M  : vcast (live cast3->vproj); later kfr(48-52)+vfr lo(52-56)
    // 52..60M  : vfr (repack_v->flash)  [48-52 kfr]
    // 60M+     : weights
    char* ws = (char*)d_ws;
    short* H1q   = (short*)(ws + 0);
    short* H1k   = (short*)(ws + 16777216);
    short* xb3   = (short*)(ws + 0);
    short* qcast = (short*)(ws + 33554432);
    short* kcast = (short*)(ws + 41943040);
    short* vcast = (short*)(ws + 50331648);
    short* qbb   = (short*)(ws + 33554432);
    short* kbb   = (short*)(ws + 37748736);
    short* vbb   = (short*)(ws + 41943040);
    short* kfr   = (short*)(ws + 50331648);
    short* vfr   = (short*)(ws + 54525952);
    short* Wq1t  = (short*)(ws + 62914560);
    short* Wk1t  = (short*)(ws + 63963136);
    short* Wq2t  = (short*)(ws + 65011712);
    short* Wk2t  = (short*)(ws + 65536000);
    short* Wvt   = (short*)(ws + 66060288);
    short* Wo3t  = (short*)(ws + 66584576);   // -> end 68,157,440

    dim3 blk(256);
    const float qscale = 0.17677669529663687f * 1.4426950408889634f;

    // input casts + weight prep
    cast3<<<dim3(2048, 3), blk, 0, stream>>>(query, key, value, qcast, kcast, vcast);
    wcast_t<<<dim3(32, 16), blk, 0, stream>>>(Wq1, Wq1t, 512, 1024);
    wcast_t<<<dim3(32, 16), blk, 0, stream>>>(Wk1, Wk1t, 512, 1024);
    wcast_t<<<dim3(8, 32), blk, 0, stream>>>(Wq2, Wq2t, 1024, 256);
    wcast_t<<<dim3(8, 32), blk, 0, stream>>>(Wk2, Wk2t, 1024, 256);
    wcast_t<<<dim3(16, 16), blk, 0, stream>>>(Wv, Wvt, 512, 512);
    wcast_t3<<<dim3(16, 16), blk, 0, stream>>>(Wo, Wo3t, 512, 512);

    // MLP layer 1 (q & k batched): GELU, bf16. N=1024, K=512, nbn=8
    gemm_bt<1, 0><<<dim3(8 * 64, 1, 2), blk, 0, stream>>>(
        qcast, kcast, Wq1t, Wk1t, bq1, bk1, H1q, H1k, 1.f, 1.f, 8, 1024, 512);
    // MLP layer 2 (q & k batched): q pre-scaled. N=256, K=1024, nbn=2
    gemm_bt<0, 0><<<dim3(2 * 64, 1, 2), blk, 0, stream>>>(
        H1q, H1k, Wq2t, Wk2t, bq2, bk2, qbb, kbb, qscale, 1.f, 2, 256, 1024);
    // v projection: N=512, K=512, nbn=4
    gemm_bt<0, 0><<<dim3(4 * 64, 1, 1), blk, 0, stream>>>(
        vcast, vcast, Wvt, Wvt, bv, bv, vbb, vbb, 1.f, 1.f, 4, 512, 512);
    // frag-major repacks for flash
    repack_k<<<dim3(64, 16), blk, 0, stream>>>(kbb, kfr);
    repack_v<<<dim3(64, 16), blk, 0, stream>>>(vbb, vfr);
    // attention: barrier-free, 2-wave blocks, key-split in-block
    flash_ks<<<dim3(128, 16), dim3(128), 0, stream>>>(qbb, kfr, vfr, xb3);
    // output projection, split-bf16 (K=1536) -> f32, nbn=4
    gemm_bt<0, 1><<<dim3(4 * 64, 1, 1), blk, 0, stream>>>(
        xb3, xb3, Wo3t, Wo3t, bo, bo, out, out, 1.f, 1.f, 4, 512, 1536);
}

// Round 9
// 308.778 us; speedup vs baseline: 1.5543x; 1.1152x over previous
//
#include <hip/hip_runtime.h>
#include <math.h>

typedef __attribute__((ext_vector_type(8))) short short8;
typedef __bf16 bf16x8 __attribute__((ext_vector_type(8)));
typedef __attribute__((ext_vector_type(4))) float f32x4;
typedef __attribute__((ext_vector_type(16))) float f32x16;

__device__ inline short f2bf(float f) {
    unsigned u = __builtin_bit_cast(unsigned, f);
    u += 0x7fff + ((u >> 16) & 1);   // round-to-nearest-even
    return (short)(u >> 16);
}
__device__ inline float bf2f(short h) {
    return __builtin_bit_cast(float, ((unsigned)(unsigned short)h) << 16);
}
__device__ inline float gelu_f(float x) {
    return 0.5f * x * (1.f + erff(x * 0.70710678118654752f));
}

// ---------------------------------------------------------------------------
// Cast query/key/value f32 -> bf16 (blockIdx.y selects tensor)
// ---------------------------------------------------------------------------
__global__ __launch_bounds__(256) void cast3(
    const float* __restrict__ q, const float* __restrict__ k,
    const float* __restrict__ v,
    short* __restrict__ qc, short* __restrict__ kc, short* __restrict__ vc)
{
    const float* src = blockIdx.y == 0 ? q : (blockIdx.y == 1 ? k : v);
    short* dst = blockIdx.y == 0 ? qc : (blockIdx.y == 1 ? kc : vc);
    size_t i = ((size_t)blockIdx.x * 256 + threadIdx.x) * 8;
    float4 a = *(const float4*)(src + i);
    float4 b = *(const float4*)(src + i + 4);
    short8 o;
    o[0] = f2bf(a.x); o[1] = f2bf(a.y); o[2] = f2bf(a.z); o[3] = f2bf(a.w);
    o[4] = f2bf(b.x); o[5] = f2bf(b.y); o[6] = f2bf(b.z); o[7] = f2bf(b.w);
    *(short8*)(void*)(dst + i) = o;
}

// ---------------------------------------------------------------------------
// W f32 [K][N] -> Wt bf16 [N][K]
// ---------------------------------------------------------------------------
__global__ __launch_bounds__(256) void wcast_t(
    const float* __restrict__ W, short* __restrict__ Wt, int K, int N)
{
    __shared__ float T[32][33];
    int k0 = blockIdx.y * 32, n0 = blockIdx.x * 32;
    int tid = threadIdx.x;
    int r = tid >> 3, c4 = (tid & 7) * 4;
    float4 v = *(const float4*)&W[(size_t)(k0 + r) * N + n0 + c4];
    T[r][c4 + 0] = v.x; T[r][c4 + 1] = v.y; T[r][c4 + 2] = v.z; T[r][c4 + 3] = v.w;
    __syncthreads();
    short4 o;
    o.x = f2bf(T[c4 + 0][r]);
    o.y = f2bf(T[c4 + 1][r]);
    o.z = f2bf(T[c4 + 2][r]);
    o.w = f2bf(T[c4 + 3][r]);
    *(short4*)&Wt[(size_t)(n0 + r) * K + k0 + c4] = o;
}

// W f32 [K][N] -> W3t bf16 [N][3K] = [hi | lo | hi]
__global__ __launch_bounds__(256) void wcast_t3(
    const float* __restrict__ W, short* __restrict__ W3t, int K, int N)
{
    __shared__ float T[32][33];
    int k0 = blockIdx.y * 32, n0 = blockIdx.x * 32;
    int tid = threadIdx.x;
    int r = tid >> 3, c4 = (tid & 7) * 4;
    float4 v = *(const float4*)&W[(size_t)(k0 + r) * N + n0 + c4];
    T[r][c4 + 0] = v.x; T[r][c4 + 1] = v.y; T[r][c4 + 2] = v.z; T[r][c4 + 3] = v.w;
    __syncthreads();
    short4 hi, lo;
    float f;
    f = T[c4 + 0][r]; hi.x = f2bf(f); lo.x = f2bf(f - bf2f(hi.x));
    f = T[c4 + 1][r]; hi.y = f2bf(f); lo.y = f2bf(f - bf2f(hi.y));
    f = T[c4 + 2][r]; hi.z = f2bf(f); lo.z = f2bf(f - bf2f(hi.z));
    f = T[c4 + 3][r]; hi.w = f2bf(f); lo.w = f2bf(f - bf2f(hi.w));
    short* d = W3t + (size_t)(n0 + r) * 3 * K + k0 + c4;
    *(short4*)d = hi;
    *(short4*)(d + K) = lo;
    *(short4*)(d + 2 * K) = hi;
}

// ---------------------------------------------------------------------------
// bf16 MFMA GEMM, B^T layout, BK=64, XCD-aware swizzle. BM=128, BN template.
// BN=128: 4 waves 2x2 of 64x64. BN=64: 4 waves 2x2 of 64x32.
// ---------------------------------------------------------------------------
template <int ACT, int OUTF32, int BN>
__global__ __launch_bounds__(256) void gemm_bt(
    const short* __restrict__ A0, const short* __restrict__ A1,
    const short* __restrict__ B0, const short* __restrict__ B1,
    const float* __restrict__ b0, const float* __restrict__ b1,
    void* C0_, void* C1_,
    float s0, float s1, int nbn, int N, int K)
{
    constexpr int NT = BN / 32;        // n-tiles per wave
    const int z = blockIdx.z;
    const short* A = z ? A1 : A0;
    const short* B = z ? B1 : B0;
    const float* bias = z ? b1 : b0;
    void* C_ = z ? C1_ : C0_;
    const float scale = z ? s1 : s0;

    const int L = blockIdx.x;
    const int xcd = L & 7;
    const int per = L >> 3;
    const int bn = (per % nbn) * BN;
    const int bm = ((per / nbn) * 8 + xcd) * 128;

    const int tid = threadIdx.x;
    const int w = tid >> 6;
    const int lane = tid & 63;
    const int l15 = lane & 15, quad = lane >> 4;
    const int wm = (w >> 1) * 64, wn = (w & 1) * (BN / 2);

    __shared__ __align__(16) short As[128 * 64];
    __shared__ __align__(16) short Bs[BN * 64];

    f32x4 acc[4][NT];
#pragma unroll
    for (int mt = 0; mt < 4; ++mt)
#pragma unroll
        for (int nt = 0; nt < NT; ++nt) acc[mt][nt] = (f32x4){0.f, 0.f, 0.f, 0.f};

    for (int k0 = 0; k0 < K; k0 += 64) {
#pragma unroll
        for (int i = 0; i < 4; ++i) {
            int ga = tid + i * 256;
            int row = ga >> 3, g = ga & 7;
            short8 aval = *(const short8*)(const void*)&A[(size_t)(bm + row) * K + k0 + g * 8];
            *(short8*)(void*)&As[row * 64 + ((g ^ (row & 7)) * 8)] = aval;
        }
#pragma unroll
        for (int i = 0; i < BN / 32; ++i) {
            int gb = tid + i * 256;
            int row = gb >> 3, g = gb & 7;
            short8 bval = *(const short8*)(const void*)&B[(size_t)(bn + row) * K + k0 + g * 8];
            *(short8*)(void*)&Bs[row * 64 + ((g ^ (row & 7)) * 8)] = bval;
        }
        __syncthreads();

#pragma unroll
        for (int ks = 0; ks < 2; ++ks) {
            bf16x8 af[4], bfr[NT];
#pragma unroll
            for (int t = 0; t < 4; ++t) {
                int row = wm + t * 16 + l15;
                af[t] = __builtin_bit_cast(bf16x8,
                    *(const short8*)(const void*)&As[row * 64 + (((ks * 4 + quad) ^ (row & 7)) * 8)]);
            }
#pragma unroll
            for (int t = 0; t < NT; ++t) {
                int row = wn + t * 16 + l15;
                bfr[t] = __builtin_bit_cast(bf16x8,
                    *(const short8*)(const void*)&Bs[row * 64 + (((ks * 4 + quad) ^ (row & 7)) * 8)]);
            }
#pragma unroll
            for (int mt = 0; mt < 4; ++mt)
#pragma unroll
                for (int nt = 0; nt < NT; ++nt)
                    acc[mt][nt] = __builtin_amdgcn_mfma_f32_16x16x32_bf16(af[mt], bfr[nt], acc[mt][nt], 0, 0, 0);
        }
        __syncthreads();
    }

    float bv[NT];
#pragma unroll
    for (int nt = 0; nt < NT; ++nt) bv[nt] = bias[bn + wn + nt * 16 + l15];
#pragma unroll
    for (int mt = 0; mt < 4; ++mt)
#pragma unroll
        for (int r = 0; r < 4; ++r) {
            int row = bm + wm + mt * 16 + quad * 4 + r;
#pragma unroll
            for (int nt = 0; nt < NT; ++nt) {
                float v = acc[mt][nt][r] + bv[nt];
                if (ACT) v = gelu_f(v);
                v *= scale;
                int col = bn + wn + nt * 16 + l15;
                if (OUTF32) ((float*)C_)[(size_t)row * N + col] = v;
                else        ((short*)C_)[(size_t)row * N + col] = f2bf(v);
            }
        }
}

// ---------------------------------------------------------------------------
// K repack: kbb bf16 [8192][256] -> kfr frag-major (proven R5)
// ---------------------------------------------------------------------------
__global__ __launch_bounds__(256) void repack_k(
    const short* __restrict__ kb, short* __restrict__ kfr)
{
    const int kt = blockIdx.x, bh = blockIdx.y;
    const int b = bh >> 3, h = bh & 7;
    const int t = threadIdx.x;
    const int c = t >> 6, l = t & 63;
    const int nt = c >> 1, ks = c & 1;
    int key = kt * 64 + nt * 32 + (l & 31);
    int k = ks * 16 + (l >> 5) * 8;
    short8 v = *(const short8*)(const void*)&kb[(size_t)(b * 4096 + key) * 256 + h * 32 + k];
    *(short8*)(void*)&kfr[((((size_t)bh * 64 + kt) * 4 + c) * 64 + l) * 8] = v;
}

// ---------------------------------------------------------------------------
// V repack: vbb bf16 [8192][512] -> vfr frag-major (proven R5)
// ---------------------------------------------------------------------------
__global__ __launch_bounds__(256) void repack_v(
    const short* __restrict__ vbb, short* __restrict__ vfr)
{
    const int kt = blockIdx.x, bh = blockIdx.y;
    const int b = bh >> 3, h = bh & 7;
    const int t = threadIdx.x;
    __shared__ short Vt[64][72];   // [key][dk]

#pragma unroll
    for (int it = 0; it < 2; ++it) {
        int idx = t + it * 256;
        int keyr = idx >> 3, c8 = (idx & 7) * 8;
        *(short8*)(void*)&Vt[keyr][c8] =
            *(const short8*)(const void*)&vbb[(size_t)(b * 4096 + kt * 64 + keyr) * 512 + h * 64 + c8];
    }
    __syncthreads();
#pragma unroll
    for (int it = 0; it < 2; ++it) {
        int chunk = (t >> 6) * 2 + it;
        int l = t & 63;
        int dt = chunk >> 2, ks = chunk & 3;
        short8 o;
#pragma unroll
        for (int j = 0; j < 8; ++j)
            o[j] = Vt[ks * 16 + (l >> 5) * 8 + j][dt * 32 + (l & 31)];
        *(short8*)(void*)&vfr[((((size_t)bh * 64 + kt) * 8 + chunk) * 64 + l) * 8] = o;
    }
}

// ---------------------------------------------------------------------------
// Barrier-free flash attention, 64 q rows/wave (2x K/V reuse vs R7).
// Block = 128 thr = 2 key-split waves; each wave: 64 q x 2048 keys, two
// q-groups g=0/1. Direct frag-major global loads, V issued early (consumed
// after QK+exp), next-K prefetch. One combine barrier at the end.
// Grid 1024 flat, XCD-swizzled: each bh's K/V (768 KB) pinned to one XCD L2.
// ---------------------------------------------------------------------------
__global__ __launch_bounds__(128, 2) void flash_ks(
    const short* __restrict__ qb, const short* __restrict__ kfr,
    const short* __restrict__ vfr, short* __restrict__ xb3)
{
    const int L = blockIdx.x;          // 0..1023
    const int xcd = L & 7;
    const int idx = L >> 3;            // 0..127
    const int bh = xcd * 2 + (idx & 1);
    const int qt = idx >> 1;           // 0..63 (64 q rows each)
    const int b = bh >> 3, h = bh & 7;
    const int wv = threadIdx.x >> 6;   // key-split 0/1
    const int lane = threadIdx.x & 63;
    const int l31 = lane & 31;
    const int half = lane >> 5;

    __shared__ __align__(16) short Pbuf[2][2][32 * 68];  // [wv][g][q 32][key 64 +4]
    __shared__ __align__(16) float redO[64][66];
    __shared__ float redl[2][64];

    // Q B-operand frags for both q-groups
    bf16x8 qf[2][2];
#pragma unroll
    for (int g = 0; g < 2; ++g) {
        const short* qrow = qb + (size_t)(b * 4096 + qt * 64 + g * 32 + l31) * 256 + h * 32 + half * 8;
        qf[g][0] = __builtin_bit_cast(bf16x8, *(const short8*)(const void*)qrow);
        qf[g][1] = __builtin_bit_cast(bf16x8, *(const short8*)(const void*)(qrow + 16));
    }

    f32x16 O[2][2];   // [g][dt]
#pragma unroll
    for (int g = 0; g < 2; ++g)
#pragma unroll
        for (int dt = 0; dt < 2; ++dt) O[g][dt] = (f32x16){};
    float la[2] = {0.f, 0.f};

    const short* kbase = kfr + ((size_t)bh * 64) * 4 * 512 + lane * 8;
    const short* vbase = vfr + ((size_t)bh * 64) * 8 * 512 + lane * 8;

    // preload K for first tile
    bf16x8 kc[4], kn[4];
    {
        const short* kp = kbase + (size_t)(wv * 32) * 4 * 512;
#pragma unroll
        for (int c = 0; c < 4; ++c)
            kc[c] = __builtin_bit_cast(bf16x8, *(const short8*)(const void*)(kp + c * 512));
    }

#pragma unroll 1
    for (int t = 0; t < 32; ++t) {
        const int kt = wv * 32 + t;
        // V loads issued now, consumed after QK+exp (~500 cyc of cover)
        bf16x8 vc[8];
        const short* vp = vbase + (size_t)kt * 8 * 512;
#pragma unroll
        for (int c = 0; c < 8; ++c)
            vc[c] = __builtin_bit_cast(bf16x8, *(const short8*)(const void*)(vp + c * 512));

        // QK^T for both q-groups: S^T[key 64][q 32] per group
        f32x16 zero{};
        f32x16 s00 = __builtin_amdgcn_mfma_f32_32x32x16_bf16(kc[0], qf[0][0], zero, 0, 0, 0);
        s00 = __builtin_amdgcn_mfma_f32_32x32x16_bf16(kc[1], qf[0][1], s00, 0, 0, 0);
        f32x16 s01 = __builtin_amdgcn_mfma_f32_32x32x16_bf16(kc[2], qf[0][0], zero, 0, 0, 0);
        s01 = __builtin_amdgcn_mfma_f32_32x32x16_bf16(kc[3], qf[0][1], s01, 0, 0, 0);
        f32x16 s10 = __builtin_amdgcn_mfma_f32_32x32x16_bf16(kc[0], qf[1][0], zero, 0, 0, 0);
        s10 = __builtin_amdgcn_mfma_f32_32x32x16_bf16(kc[1], qf[1][1], s10, 0, 0, 0);
        f32x16 s11 = __builtin_amdgcn_mfma_f32_32x32x16_bf16(kc[2], qf[1][0], zero, 0, 0, 0);
        s11 = __builtin_amdgcn_mfma_f32_32x32x16_bf16(kc[3], qf[1][1], s11, 0, 0, 0);

        // kc consumed -> prefetch next tile's K (completes during exp+PV)
        if (t < 31) {
            const short* kp = kbase + (size_t)(kt + 1) * 4 * 512;
#pragma unroll
            for (int c = 0; c < 4; ++c)
                kn[c] = __builtin_bit_cast(bf16x8, *(const short8*)(const void*)(kp + c * 512));
        }

        // exp + l accumulate + P -> LDS (bf16, b64 packs), per group
#pragma unroll
        for (int g = 0; g < 2; ++g) {
            short* Pw = &Pbuf[wv][g][0];
#pragma unroll
            for (int nt = 0; nt < 2; ++nt) {
                const f32x16& s = g ? (nt ? s11 : s10) : (nt ? s01 : s00);
#pragma unroll
                for (int r2 = 0; r2 < 4; ++r2) {
                    short4 pk;
                    float p0 = __builtin_amdgcn_exp2f(s[r2 * 4 + 0]);
                    float p1 = __builtin_amdgcn_exp2f(s[r2 * 4 + 1]);
                    float p2 = __builtin_amdgcn_exp2f(s[r2 * 4 + 2]);
                    float p3 = __builtin_amdgcn_exp2f(s[r2 * 4 + 3]);
                    la[g] += (p0 + p1) + (p2 + p3);
                    pk.x = f2bf(p0); pk.y = f2bf(p1); pk.z = f2bf(p2); pk.w = f2bf(p3);
                    *(short4*)(void*)&Pw[l31 * 68 + nt * 32 + r2 * 8 + half * 4] = pk;
                }
            }
        }

        // PV for both groups
#pragma unroll
        for (int g = 0; g < 2; ++g) {
            const short* Pw = &Pbuf[wv][g][0];
            bf16x8 pf[4];
#pragma unroll
            for (int ks = 0; ks < 4; ++ks)
                pf[ks] = __builtin_bit_cast(bf16x8,
                    *(const short8*)(const void*)&Pw[l31 * 68 + ks * 16 + half * 8]);
#pragma unroll
            for (int ks = 0; ks < 4; ++ks) {
                O[g][0] = __builtin_amdgcn_mfma_f32_32x32x16_bf16(pf[ks], vc[ks], O[g][0], 0, 0, 0);
                O[g][1] = __builtin_amdgcn_mfma_f32_32x32x16_bf16(pf[ks], vc[4 + ks], O[g][1], 0, 0, 0);
            }
        }

#pragma unroll
        for (int c = 0; c < 4; ++c) kc[c] = kn[c];
    }

    // la: this lane's key subset; xor-32 adds the other half's keys
#pragma unroll
    for (int g = 0; g < 2; ++g) la[g] += __shfl_xor(la[g], 32);

    // ---- combine the two key-halves ----
    if (half == 0) {
        redl[wv][0 * 32 + l31] = la[0];
        redl[wv][1 * 32 + l31] = la[1];
    }
    if (wv == 1) {
#pragma unroll
        for (int g = 0; g < 2; ++g)
#pragma unroll
            for (int r = 0; r < 16; ++r) {
                int q = g * 32 + (r & 3) + 8 * (r >> 2) + 4 * half;
                redO[q][l31] = O[g][0][r];
                redO[q][32 + l31] = O[g][1][r];
            }
    }
    __syncthreads();
    if (wv == 0) {
#pragma unroll
        for (int g = 0; g < 2; ++g)
#pragma unroll
            for (int r = 0; r < 16; ++r) {
                int q = g * 32 + (r & 3) + 8 * (r >> 2) + 4 * half;
                float o0 = O[g][0][r] + redO[q][l31];
                float o1 = O[g][1][r] + redO[q][32 + l31];
                float inv = 1.f / (redl[0][q] + redl[1][q]);
                float x0 = o0 * inv, x1 = o1 * inv;
                short hi0 = f2bf(x0), hi1 = f2bf(x1);
                short lo0 = f2bf(x0 - bf2f(hi0)), lo1 = f2bf(x1 - bf2f(hi1));
                size_t row = (size_t)(b * 4096 + qt * 64 + q);
                short* d = xb3 + row * 1536 + h * 64 + l31;
                d[0] = hi0;    d[32] = hi1;
                d[512] = hi0;  d[544] = hi1;
                d[1024] = lo0; d[1056] = lo1;
            }
    }
}

// ---------------------------------------------------------------------------
extern "C" void kernel_launch(void* const* d_in, const int* in_sizes, int n_in,
                              void* d_out, int out_size, void* d_ws, size_t ws_size,
                              hipStream_t stream)
{
    const float* query = (const float*)d_in[0];
    const float* key   = (const float*)d_in[1];
    const float* value = (const float*)d_in[2];
    const float* Wq1   = (const float*)d_in[3];
    const float* bq1   = (const float*)d_in[4];
    const float* Wq2   = (const float*)d_in[5];
    const float* bq2   = (const float*)d_in[6];
    const float* Wk1   = (const float*)d_in[7];
    const float* bk1   = (const float*)d_in[8];
    const float* Wk2   = (const float*)d_in[9];
    const float* bk2   = (const float*)d_in[10];
    const float* Wv    = (const float*)d_in[11];
    const float* bv    = (const float*)d_in[12];
    const float* Wo    = (const float*)d_in[13];
    const float* bo    = (const float*)d_in[14];
    float* out = (float*)d_out;

    // Workspace (bytes), total 68 MB with overlays (proven R8):
    char* ws = (char*)d_ws;
    short* H1q   = (short*)(ws + 0);
    short* H1k   = (short*)(ws + 16777216);
    short* xb3   = (short*)(ws + 0);
    short* qcast = (short*)(ws + 33554432);
    short* kcast = (short*)(ws + 41943040);
    short* vcast = (short*)(ws + 50331648);
    short* qbb   = (short*)(ws + 33554432);
    short* kbb   = (short*)(ws + 37748736);
    short* vbb   = (short*)(ws + 41943040);
    short* kfr   = (short*)(ws + 50331648);
    short* vfr   = (short*)(ws + 54525952);
    short* Wq1t  = (short*)(ws + 62914560);
    short* Wk1t  = (short*)(ws + 63963136);
    short* Wq2t  = (short*)(ws + 65011712);
    short* Wk2t  = (short*)(ws + 65536000);
    short* Wvt   = (short*)(ws + 66060288);
    short* Wo3t  = (short*)(ws + 66584576);   // -> end 68,157,440

    dim3 blk(256);
    const float qscale = 0.17677669529663687f * 1.4426950408889634f;

    // input casts + weight prep
    cast3<<<dim3(2048, 3), blk, 0, stream>>>(query, key, value, qcast, kcast, vcast);
    wcast_t<<<dim3(32, 16), blk, 0, stream>>>(Wq1, Wq1t, 512, 1024);
    wcast_t<<<dim3(32, 16), blk, 0, stream>>>(Wk1, Wk1t, 512, 1024);
    wcast_t<<<dim3(8, 32), blk, 0, stream>>>(Wq2, Wq2t, 1024, 256);
    wcast_t<<<dim3(8, 32), blk, 0, stream>>>(Wk2, Wk2t, 1024, 256);
    wcast_t<<<dim3(16, 16), blk, 0, stream>>>(Wv, Wvt, 512, 512);
    wcast_t3<<<dim3(16, 16), blk, 0, stream>>>(Wo, Wo3t, 512, 512);

    // MLP layer 1 (q & k batched): GELU, bf16. N=1024, K=512, BN=128, nbn=8
    gemm_bt<1, 0, 128><<<dim3(8 * 64, 1, 2), blk, 0, stream>>>(
        qcast, kcast, Wq1t, Wk1t, bq1, bk1, H1q, H1k, 1.f, 1.f, 8, 1024, 512);
    // MLP layer 2 (q & k batched): q pre-scaled. N=256, K=1024, BN=64, nbn=4
    gemm_bt<0, 0, 64><<<dim3(4 * 64, 1, 2), blk, 0, stream>>>(
        H1q, H1k, Wq2t, Wk2t, bq2, bk2, qbb, kbb, qscale, 1.f, 4, 256, 1024);
    // v projection: N=512, K=512, BN=64, nbn=8
    gemm_bt<0, 0, 64><<<dim3(8 * 64, 1, 1), blk, 0, stream>>>(
        vcast, vcast, Wvt, Wvt, bv, bv, vbb, vbb, 1.f, 1.f, 8, 512, 512);
    // frag-major repacks for flash
    repack_k<<<dim3(64, 16), blk, 0, stream>>>(kbb, kfr);
    repack_v<<<dim3(64, 16), blk, 0, stream>>>(vbb, vfr);
    // attention: barrier-free, 64 q rows/wave, key-split, XCD-swizzled
    flash_ks<<<dim3(1024), dim3(128), 0, stream>>>(qbb, kfr, vfr, xb3);
    // output projection, split-bf16 (K=1536) -> f32, BN=64, nbn=8
    gemm_bt<0, 1, 64><<<dim3(8 * 64, 1, 1), blk, 0, stream>>>(
        xb3, xb3, Wo3t, Wo3t, bo, bo, out, out, 1.f, 1.f, 8, 512, 1536);
}